// Round 2
// baseline (705.248 us; speedup 1.0000x reference)
//
#include <hip/hip_runtime.h>

// out[b,g,h,w] = sum_n x[b, IDX[g,n], h, w] * w[g,n]
// IDX[g,n] = (g/4)*16 + n*4 + (g%4)   (bijection over 64 channels)
// B=8, C=64, G=16, N=4, HW=512*512.
// Pure streaming, zero reuse: 512 MiB read + 128 MiB write -> ~107 us floor
// at 6.3 TB/s achievable.
//
// R2: burst-lengthening. Each thread handles 2 consecutive float4 (32 B/lane)
// per channel -> every wave-level burst (4 read streams + 1 write stream)
// doubles from 1 KiB to 2 KiB contiguous, improving DRAM row-buffer locality
// for the mixed-stream pattern. 8 NT loads + 2 NT stores per thread,
// ~56 VGPRs -> full 8-wave/SIMD occupancy retained.

#define B_    8
#define C_    64
#define G_    16
#define HW4_  65536            // 512*512/4 (float4 units)
#define HW8_  32768            // float4-PAIR units per plane
#define BLOCK_ 256

typedef float v4f __attribute__((ext_vector_type(4)));

__global__ __launch_bounds__(BLOCK_) void binnings_kernel(
    const v4f* __restrict__ x,     // (B, C, HW4) in float4 units
    const v4f* __restrict__ w4,    // (G) : w4[g] = w[g,0..3]
    v4f* __restrict__ out)         // (B, G, HW4)
{
    const int tid = blockIdx.x * BLOCK_ + threadIdx.x;  // [0, B*G*HW8)
    const int hw8 = tid & (HW8_ - 1);
    const int bg  = tid >> 15;          // tid / HW8_
    const int g   = bg & (G_ - 1);      // wave-uniform
    const int b   = bg >> 4;            // wave-uniform
    const int c0  = ((g >> 2) << 4) + (g & 3);

    const v4f w = w4[g];                // 256 B table, stays cached

    const v4f* xp = x + ((size_t)(b * C_ + c0)) * HW4_ + 2 * hw8;

    // 2 consecutive float4 per summed channel: adjacent addresses fold into
    // one base + offset:16, and each wave reads 2 KiB contiguous per stream.
    const v4f a00 = __builtin_nontemporal_load(xp);
    const v4f a01 = __builtin_nontemporal_load(xp + 1);
    const v4f a10 = __builtin_nontemporal_load(xp + (size_t)4  * HW4_);
    const v4f a11 = __builtin_nontemporal_load(xp + (size_t)4  * HW4_ + 1);
    const v4f a20 = __builtin_nontemporal_load(xp + (size_t)8  * HW4_);
    const v4f a21 = __builtin_nontemporal_load(xp + (size_t)8  * HW4_ + 1);
    const v4f a30 = __builtin_nontemporal_load(xp + (size_t)12 * HW4_);
    const v4f a31 = __builtin_nontemporal_load(xp + (size_t)12 * HW4_ + 1);

    const v4f o0 = a00 * w.x + a10 * w.y + a20 * w.z + a30 * w.w;
    const v4f o1 = a01 * w.x + a11 * w.y + a21 * w.z + a31 * w.w;

    v4f* op = out + (size_t)bg * HW4_ + 2 * hw8;
    __builtin_nontemporal_store(o0, op);
    __builtin_nontemporal_store(o1, op + 1);
}

extern "C" void kernel_launch(void* const* d_in, const int* in_sizes, int n_in,
                              void* d_out, int out_size, void* d_ws, size_t ws_size,
                              hipStream_t stream) {
    const v4f* x  = (const v4f*)d_in[0];   // (8,64,512,512) f32
    const v4f* w4 = (const v4f*)d_in[1];   // (16,4,1,1) f32
    v4f* out = (v4f*)d_out;                // (8,16,512,512) f32

    const int total = B_ * G_ * HW8_;      // 4,194,304 threads
    const int grid  = total / BLOCK_;      // 16384 blocks
    binnings_kernel<<<grid, BLOCK_, 0, stream>>>(x, w4, out);
}